// Round 7
// baseline (872.983 us; speedup 1.0000x reference)
//
#include <hip/hip_runtime.h>
#include <hip/hip_bf16.h>
#include <cstdint>

// MoEExperts: x[4096,2048] f32, top-2 of 8 experts,
// w1/w3 [8,2048,4096] (K-major [K][N]), w2 [8,4096,2048], out [4096,2048] f32.
#define T_TOKENS 4096
#define HID      2048
#define INTER    4096
#define NEXP     8
#define TOPK     2
#define NPAIRS   (T_TOKENS * TOPK)          // 8192
#define BM 256
#define BN 128
#define BK 64
#define MAXROWS  (NPAIRS + NEXP * BM)       // 10240
#define NRB2     32                          // worst-case per-expert row-blocks (8192/256)

typedef __attribute__((ext_vector_type(8))) short   short8;
typedef __attribute__((ext_vector_type(4))) float   f32x4;
typedef __attribute__((ext_vector_type(8))) ushort  ushort8v;

static __device__ __forceinline__ ushort f2bf(float f) {
    __hip_bfloat16 b = __float2bfloat16(f);
    return __builtin_bit_cast(ushort, b);
}

typedef const __attribute__((address_space(1))) unsigned char ga_u8;
typedef __attribute__((address_space(3))) unsigned char       la_u8;
static __device__ __forceinline__ void gl_lds16(const void* g, void* l) {
    __builtin_amdgcn_global_load_lds((ga_u8*)g, (la_u8*)l, 16, 0, 0);
}

// raw barrier with code-motion fences (no vmcnt drain, unlike __syncthreads)
#define SBAR() do { __builtin_amdgcn_sched_barrier(0); \
                    __builtin_amdgcn_s_barrier(); \
                    __builtin_amdgcn_sched_barrier(0); \
                    asm volatile("" ::: "memory"); } while (0)
#define VMCNT(n) do { asm volatile("s_waitcnt vmcnt(" #n ")" ::: "memory"); \
                      __builtin_amdgcn_sched_barrier(0); } while (0)

// ---------------- routing -------------------------------------------------
__global__ void route_kernel(const int* __restrict__ eidx,
                             const float* __restrict__ ew,
                             int* __restrict__ cnt, int* __restrict__ pbase,
                             int* __restrict__ tokl, float* __restrict__ wgtl) {
    __shared__ int s_cnt[NEXP];
    __shared__ int s_pos[NEXP];
    __shared__ int s_base[NEXP];
    int tid = threadIdx.x;
    if (tid < NEXP) { s_cnt[tid] = 0; s_pos[tid] = 0; }
    __syncthreads();
    for (int p = tid; p < NPAIRS; p += blockDim.x)
        atomicAdd(&s_cnt[eidx[p]], 1);
    __syncthreads();
    if (tid == 0) {
        int b = 0;
        for (int e = 0; e < NEXP; ++e) {
            s_base[e] = b;
            cnt[e]    = s_cnt[e];
            pbase[e]  = b;
            b += (s_cnt[e] + BM - 1) / BM * BM;   // pad to 256
        }
        pbase[NEXP] = b;
    }
    __syncthreads();
    for (int p = tid; p < NPAIRS; p += blockDim.x) {
        int e   = eidx[p];
        int pos = atomicAdd(&s_pos[e], 1);
        int row = s_base[e] + pos;
        tokl[row] = p >> 1;
        wgtl[row] = ew[p];
    }
}

// ---------------- x fp32 -> bf16 ------------------------------------------
__global__ __launch_bounds__(256) void cvt_x_kernel(const float* __restrict__ x,
                                                    ushort* __restrict__ xbf) {
    int i = (blockIdx.x * 256 + threadIdx.x) * 8;
    float4 a = *reinterpret_cast<const float4*>(x + i);
    float4 b = *reinterpret_cast<const float4*>(x + i + 4);
    ushort8v o;
    o[0] = f2bf(a.x); o[1] = f2bf(a.y); o[2] = f2bf(a.z); o[3] = f2bf(a.w);
    o[4] = f2bf(b.x); o[5] = f2bf(b.y); o[6] = f2bf(b.z); o[7] = f2bf(b.w);
    *reinterpret_cast<ushort8v*>(xbf + i) = o;
}

// ---------------- weight transpose+convert: fp32 [K][N] -> bf16 [N][K] -----
__global__ __launch_bounds__(256) void transpose_cvt_kernel(
        const float* __restrict__ src, ushort* __restrict__ dst,
        int K, int N, int c0, int CN, long estride) {
    int ez = blockIdx.z;
    const float* s = src + (size_t)ez * estride;
    ushort* d = dst + (size_t)ez * CN * K;
    int nb = blockIdx.x * 64 + c0;
    int kb = blockIdx.y * 64;
    __shared__ ushort t[64][72];
    int tid = threadIdx.x;
    int kr = tid >> 2;
    int ns = tid & 3;
    #pragma unroll
    for (int p = 0; p < 4; ++p) {
        int f = ns + p * 4;
        float4 v = *reinterpret_cast<const float4*>(&s[(size_t)(kb + kr) * N + nb + f * 4]);
        t[f * 4 + 0][kr] = f2bf(v.x);
        t[f * 4 + 1][kr] = f2bf(v.y);
        t[f * 4 + 2][kr] = f2bf(v.z);
        t[f * 4 + 3][kr] = f2bf(v.w);
    }
    __syncthreads();
    int nr = tid >> 2;
    #pragma unroll
    for (int p = 0; p < 2; ++p) {
        int ks = ((tid & 3) + p * 4) * 8;
        ushort8v v8 = *reinterpret_cast<const ushort8v*>(&t[nr][ks]);
        *reinterpret_cast<ushort8v*>(&d[(size_t)(nb - c0 + nr) * K + kb + ks]) = v8;
    }
}

// ---------------- ffn1: h = silu(x@w1) * (x@w3) ----------------------------
// BM=256 x BN=128, BK=64, 8 waves (4M x 2N), counted-vmcnt 4-phase schedule.
// LDS per buf: A 32KB @0, B1 16KB @32768, B3 16KB @49152 -> 64KB; 2 bufs = 128KB.
__global__ __launch_bounds__(512, 2) void ffn1_kernel(
        const ushort* __restrict__ xbf,
        const ushort* __restrict__ wT1, const ushort* __restrict__ wT3,
        const int* __restrict__ cnt, const int* __restrict__ pbase,
        const int* __restrict__ tokl, ushort* __restrict__ h,
        int ncb, int c0) {
    int d = blockIdx.x;
    int xcd = d & 7, q = d >> 3;
    int gq = q / NRB2, rb = q % NRB2;
    int g = gq * 8 + xcd;
    int ez = g / ncb, cb = g - ez * ncb;
    int ce = cnt[ez];                       // note: e-offset handled by caller region
    int e = ez;                             // EG path passes full expert set
    (void)e;
    int r0 = rb * BM;
    // caller passes cnt/pbase offset via pointer; ez indexes group-local expert
    // (see kernel_launch: cnt+e0, pbase+e0, wT region is [ez][CN][HID])
    if (r0 >= ce) return;
    int base = pbase[ez];

    __shared__ char lds[131072];
    char* Lb = lds;

    int tid  = threadIdx.x;
    int lane = tid & 63, wid = tid >> 6;
    int wr = (wid >> 1) * 64, wc = (wid & 1) * 64;
    int rlow = lane & 15, khi = lane >> 4;

    // ---- staging source pointers (per thread) ----
    int rr = tid >> 3;                       // 0..63
    int ss = (tid & 7) ^ (rr & 7);           // swizzled source k-slot
    const ushort* pA[4];
    #pragma unroll
    for (int i = 0; i < 4; ++i) {
        int row = r0 + i * 64 + rr;
        int tok = (row < ce) ? tokl[base + row] : 0;
        pA[i] = xbf + (size_t)tok * HID + ss * 8;
    }
    size_t wrow = (size_t)ez * ((size_t)ncb * 128) + (size_t)cb * 128;  // = ez*CN + cb*128
    const ushort* pB1[2];
    const ushort* pB3[2];
    #pragma unroll
    for (int i = 0; i < 2; ++i) {
        pB1[i] = wT1 + (wrow + i * 64 + rr) * HID + ss * 8;
        pB3[i] = wT3 + (wrow + i * 64 + rr) * HID + ss * 8;
    }
    int ldst = wid << 10;  // wave-uniform LDS dest offset

    // ---- fragment read offsets (swizzled) ----
    int aoffs[4][2], boffs[4][2];
    #pragma unroll
    for (int mi = 0; mi < 4; ++mi)
        #pragma unroll
        for (int kh = 0; kh < 2; ++kh) {
            int sw = (((kh << 2) + khi) ^ (lane & 7)) << 4;
            aoffs[mi][kh] = (wr + mi * 16 + rlow) * 128 + sw;
            boffs[mi][kh] = (wc + mi * 16 + rlow) * 128 + sw;
        }

    f32x4 accg[4][4], accu[4][4];
    #pragma unroll
    for (int i = 0; i < 4; ++i)
        #pragma unroll
        for (int j = 0; j < 4; ++j) { accg[i][j] = (f32x4)0.f; accu[i][j] = (f32x4)0.f; }

    // ---- prologue: stage tile 0 into buf 0 ----
    {
        char* L = Lb;
        #pragma unroll
        for (int i = 0; i < 4; ++i) gl_lds16(pA[i], L + i * 8192 + ldst);
        #pragma unroll
        for (int i = 0; i < 2; ++i) gl_lds16(pB1[i], L + 32768 + i * 8192 + ldst);
        #pragma unroll
        for (int i = 0; i < 2; ++i) gl_lds16(pB3[i], L + 49152 + i * 8192 + ldst);
    }

    const int NT = HID / BK;   // 32
    #pragma unroll 1
    for (int t = 0; t < NT; ++t) {
        char* Lc = Lb + ((t & 1) ? 65536 : 0);
        char* Ln = Lb + ((t & 1) ? 0 : 65536);
        int adv = (t + 1) * 64;
        bool more = (t + 1 < NT);
        if (more) {
            gl_lds16(pA[0] + adv, Ln + 0 * 8192 + ldst);
            gl_lds16(pA[1] + adv, Ln + 1 * 8192 + ldst);
            VMCNT(2);
        } else {
            VMCNT(0);
        }
        SBAR();
        // ---- phase 0: A frags + B1 ni0,1 -> accg[*][0..1]
        short8 af[4][2];
        #pragma unroll
        for (int mi = 0; mi < 4; ++mi)
            #pragma unroll
            for (int kh = 0; kh < 2; ++kh)
                af[mi][kh] = *reinterpret_cast<const short8*>(Lc + aoffs[mi][kh]);
        short8 bf[2][2];
        #pragma unroll
        for (int ni = 0; ni < 2; ++ni)
            #pragma unroll
            for (int kh = 0; kh < 2; ++kh)
                bf[ni][kh] = *reinterpret_cast<const short8*>(Lc + 32768 + boffs[ni][kh]);
        if (more) {
            gl_lds16(pA[2] + adv, Ln + 2 * 8192 + ldst);
            gl_lds16(pA[3] + adv, Ln + 3 * 8192 + ldst);
        }
        __builtin_amdgcn_s_setprio(1);
        #pragma unroll
        for (int ni = 0; ni < 2; ++ni)
            #pragma unroll
            for (int mi = 0; mi < 4; ++mi)
                #pragma unroll
                for (int kh = 0; kh < 2; ++kh)
                    accg[mi][ni] = __builtin_amdgcn_mfma_f32_16x16x32_bf16(af[mi][kh], bf[ni][kh], accg[mi][ni], 0, 0, 0);
        __builtin_amdgcn_s_setprio(0);
        SBAR();
        // ---- phase 1: B3 ni0,1 -> accu[*][0..1]
        #pragma unroll
        for (int ni = 0; ni < 2; ++ni)
            #pragma unroll
            for (int kh = 0; kh < 2; ++kh)
                bf[ni][kh] = *reinterpret_cast<const short8*>(Lc + 49152 + boffs[ni][kh]);
        if (more) {
            gl_lds16(pB1[0] + adv, Ln + 32768 + ldst);
            gl_lds16(pB1[1] + adv, Ln + 32768 + 8192 + ldst);
        }
        __builtin_amdgcn_s_setprio(1);
        #pragma unroll
        for (int ni = 0; ni < 2; ++ni)
            #pragma unroll
            for (int mi = 0; mi < 4; ++mi)
                #pragma unroll
                for (int kh = 0; kh < 2; ++kh)
                    accu[mi][ni] = __builtin_amdgcn_mfma_f32_16x16x32_bf16(af[mi][kh], bf[ni][kh], accu[mi][ni], 0, 0, 0);
        __builtin_amdgcn_s_setprio(0);
        SBAR();
        // ---- phase 2: B1 ni2,3 -> accg[*][2..3]
        #pragma unroll
        for (int ni = 0; ni < 2; ++ni)
            #pragma unroll
            for (int kh = 0; kh < 2; ++kh)
                bf[ni][kh] = *reinterpret_cast<const short8*>(Lc + 32768 + boffs[ni + 2][kh]);
        if (more) {
            gl_lds16(pB3[0] + adv, Ln + 49152 + ldst);
            gl_lds16(pB3[1] + adv, Ln + 49152 + 8192 + ldst);
        }
        __builtin_amdgcn_s_setprio(1);
        #pragma unroll
        for (int ni = 0; ni < 2; ++ni)
            #pragma unroll
            for (int mi = 0; mi < 4; ++mi)
                #pragma unroll
                for (int kh = 0; kh < 2; ++kh)
                    accg[mi][ni + 2] = __builtin_amdgcn_mfma_f32_16x16x32_bf16(af[mi][kh], bf[ni][kh], accg[mi][ni + 2], 0, 0, 0);
        __builtin_amdgcn_s_setprio(0);
        SBAR();
        // ---- phase 3: B3 ni2,3 -> accu[*][2..3]
        #pragma unroll
        for (int ni = 0; ni < 2; ++ni)
            #pragma unroll
            for (int kh = 0; kh < 2; ++kh)
                bf[ni][kh] = *reinterpret_cast<const short8*>(Lc + 49152 + boffs[ni + 2][kh]);
        __builtin_amdgcn_s_setprio(1);
        #pragma unroll
        for (int ni = 0; ni < 2; ++ni)
            #pragma unroll
            for (int mi = 0; mi < 4; ++mi)
                #pragma unroll
                for (int kh = 0; kh < 2; ++kh)
                    accu[mi][ni + 2] = __builtin_amdgcn_mfma_f32_16x16x32_bf16(af[mi][kh], bf[ni][kh], accu[mi][ni + 2], 0, 0, 0);
        __builtin_amdgcn_s_setprio(0);
        SBAR();
    }

    // ---- epilogue ----
    int hcol = c0 + cb * 128 + wc + rlow;
    #pragma unroll
    for (int mi = 0; mi < 4; ++mi) {
        #pragma unroll
        for (int q2 = 0; q2 < 4; ++q2) {
            int r = r0 + wr + mi * 16 + khi * 4 + q2;
            if (r >= ce) continue;
            ushort* hp = h + (size_t)(base + r) * INTER + hcol;
            #pragma unroll
            for (int ni = 0; ni < 4; ++ni) {
                float gg = accg[mi][ni][q2];
                float uu = accu[mi][ni][q2];
                float s = gg / (1.f + __expf(-gg));
                hp[ni * 16] = f2bf(s * uu);
            }
        }
    }
}

// ---------------- ffn2: out += wgt * (h @ w2) ------------------------------
// BM=256 x BN=128, BK=64, 8 waves, 2-phase counted-vmcnt schedule.
// LDS per buf: A 32KB @0, B 16KB @32768 -> 48KB; 2 bufs = 96KB.
__global__ __launch_bounds__(512, 2) void ffn2_kernel(
        const ushort* __restrict__ h,
        const ushort* __restrict__ wT2,
        const int* __restrict__ cnt, const int* __restrict__ pbase,
        const int* __restrict__ tokl, const float* __restrict__ wgtl,
        float* __restrict__ out, int ncb, int c0) {
    int d = blockIdx.x;
    int xcd = d & 7, q = d >> 3;
    int gq = q / NRB2, rb = q % NRB2;
    int g = gq * 8 + xcd;
    int ez = g / ncb, cb = g - ez * ncb;
    int ce = cnt[ez];
    int r0 = rb * BM;
    if (r0 >= ce) return;
    int base = pbase[ez];

    __shared__ char lds[98304];
    char* Lb = lds;

    int tid  = threadIdx.x;
    int lane = tid & 63, wid = tid >> 6;
    int wr = (wid >> 1) * 64, wc = (wid & 1) * 64;
    int rlow = lane & 15, khi = lane >> 4;

    int rr = tid >> 3;
    int ss = (tid & 7) ^ (rr & 7);
    const ushort* pA[4];
    #pragma unroll
    for (int i = 0; i < 4; ++i)
        pA[i] = h + (size_t)(base + r0 + i * 64 + rr) * INTER + ss * 8;
    size_t wrow = (size_t)ez * ((size_t)ncb * 128) + (size_t)cb * 128;
    const ushort* pB[2];
    #pragma unroll
    for (int i = 0; i < 2; ++i)
        pB[i] = wT2 + (wrow + i * 64 + rr) * INTER + ss * 8;
    int ldst = wid << 10;

    int aoffs[4][2], boffs[4][2];
    #pragma unroll
    for (int mi = 0; mi < 4; ++mi)
        #pragma unroll
        for (int kh = 0; kh < 2; ++kh) {
            int sw = (((kh << 2) + khi) ^ (lane & 7)) << 4;
            aoffs[mi][kh] = (wr + mi * 16 + rlow) * 128 + sw;
            boffs[mi][kh] = (wc + mi * 16 + rlow) * 128 + sw;
        }

    f32x4 acc[4][4];
    #pragma unroll
    for (int i = 0; i < 4; ++i)
        #pragma unroll
        for (int j = 0; j < 4; ++j) acc[i][j] = (f32x4)0.f;

    {
        char* L = Lb;
        #pragma unroll
        for (int i = 0; i < 4; ++i) gl_lds16(pA[i], L + i * 8192 + ldst);
        #pragma unroll
        for (int i = 0; i < 2; ++i) gl_lds16(pB[i], L + 32768 + i * 8192 + ldst);
    }

    const int NT = INTER / BK;   // 64
    #pragma unroll 1
    for (int t = 0; t < NT; ++t) {
        char* Lc = Lb + ((t & 1) ? 49152 : 0);
        char* Ln = Lb + ((t & 1) ? 0 : 49152);
        int adv = (t + 1) * 64;
        bool more = (t + 1 < NT);
        if (more) {
            gl_lds16(pA[0] + adv, Ln + 0 * 8192 + ldst);
            gl_lds16(pA[1] + adv, Ln + 1 * 8192 + ldst);
            VMCNT(2);
        } else {
            VMCNT(0);
        }
        SBAR();
        // ---- phase 0
        short8 af[4][2];
        #pragma unroll
        for (int mi = 0; mi < 4; ++mi)
            #pragma unroll
            for (int kh = 0; kh < 2; ++kh)
                af[mi][kh] = *reinterpret_cast<const short8*>(Lc + aoffs[mi][kh]);
        short8 bf[2][2];
        #pragma unroll
        for (int ni = 0; ni < 2; ++ni)
            #pragma unroll
            for (int kh = 0; kh < 2; ++kh)
                bf[ni][kh] = *reinterpret_cast<const short8*>(Lc + 32768 + boffs[ni][kh]);
        if (more) {
            gl_lds16(pA[2] + adv, Ln + 2 * 8192 + ldst);
            gl_lds16(pA[3] + adv, Ln + 3 * 8192 + ldst);
        }
        __builtin_amdgcn_s_setprio(1);
        #pragma unroll
        for (int ni = 0; ni < 2; ++ni)
            #pragma unroll
            for (int mi = 0; mi < 4; ++mi)
                #pragma unroll
                for (int kh = 0; kh < 2; ++kh)
                    acc[mi][ni] = __builtin_amdgcn_mfma_f32_16x16x32_bf16(af[mi][kh], bf[ni][kh], acc[mi][ni], 0, 0, 0);
        __builtin_amdgcn_s_setprio(0);
        SBAR();
        // ---- phase 1
        #pragma unroll
        for (int ni = 0; ni < 2; ++ni)
            #pragma unroll
            for (int kh = 0; kh < 2; ++kh)
                bf[ni][kh] = *reinterpret_cast<const short8*>(Lc + 32768 + boffs[ni + 2][kh]);
        if (more) {
            gl_lds16(pB[0] + adv, Ln + 32768 + ldst);
            gl_lds16(pB[1] + adv, Ln + 32768 + 8192 + ldst);
        }
        __builtin_amdgcn_s_setprio(1);
        #pragma unroll
        for (int ni = 0; ni < 2; ++ni)
            #pragma unroll
            for (int mi = 0; mi < 4; ++mi)
                #pragma unroll
                for (int kh = 0; kh < 2; ++kh)
                    acc[mi][ni + 2] = __builtin_amdgcn_mfma_f32_16x16x32_bf16(af[mi][kh], bf[ni][kh], acc[mi][ni + 2], 0, 0, 0);
        __builtin_amdgcn_s_setprio(0);
        SBAR();
    }

    int ocol = c0 + cb * 128 + wc + rlow;
    #pragma unroll
    for (int mi = 0; mi < 4; ++mi) {
        #pragma unroll
        for (int q2 = 0; q2 < 4; ++q2) {
            int r = r0 + wr + mi * 16 + khi * 4 + q2;
            if (r >= ce) continue;
            int tok  = tokl[base + r];
            float wv = wgtl[base + r];
            float* op = out + (size_t)tok * HID + ocol;
            #pragma unroll
            for (int ni = 0; ni < 4; ++ni)
                atomicAdd(&op[ni * 16], wv * acc[mi][ni][q2]);
        }
    }
}

extern "C" void kernel_launch(void* const* d_in, const int* in_sizes, int n_in,
                              void* d_out, int out_size, void* d_ws, size_t ws_size,
                              hipStream_t stream) {
    (void)in_sizes; (void)n_in; (void)out_size;
    const float* x   = (const float*)d_in[0];
    const float* ew  = (const float*)d_in[1];
    const float* w1  = (const float*)d_in[2];
    const float* w2  = (const float*)d_in[3];
    const float* w3  = (const float*)d_in[4];
    const int*  eidx = (const int*)d_in[5];
    float* out = (float*)d_out;

    int*   cnt   = (int*)d_ws;
    int*   pbase = cnt + 8;
    int*   tokl  = cnt + 32;
    float* wgtl  = (float*)(tokl + MAXROWS);
    ushort* xbf  = (ushort*)((((uintptr_t)(wgtl + MAXROWS)) + 255) & ~(uintptr_t)255);
    ushort* h    = xbf + (size_t)T_TOKENS * HID;
    ushort* region = h + (size_t)MAXROWS * INTER;
    size_t region_bytes = ws_size - ((char*)region - (char*)d_ws);

    hipMemsetAsync(d_out, 0, (size_t)T_TOKENS * HID * sizeof(float), stream);
    route_kernel<<<1, 256, 0, stream>>>(eidx, ew, cnt, pbase, tokl, wgtl);
    cvt_x_kernel<<<T_TOKENS * HID / 8 / 256, 256, 0, stream>>>(x, xbf);

    const size_t per_e1 = (size_t)2 * INTER * HID * 2;   // 33.55 MB
    const size_t per_e2 = (size_t)HID * INTER * 2;       // 16.78 MB

    // ---- stage 1: transpose w1/w3 + ffn1 ----
    if (region_bytes >= per_e1) {
        int EG = (int)(region_bytes / per_e1); if (EG > 8) EG = 8;
        for (int g = 0; g < NEXP; g += EG) {
            int ne = (NEXP - g < EG) ? (NEXP - g) : EG;
            ushort* wt1 = region;
            ushort* wt3 = region + (size_t)ne * INTER * HID;
            transpose_cvt_kernel<<<dim3(INTER / 64, HID / 64, ne), 256, 0, stream>>>(
                w1 + (size_t)g * HID * INTER, wt1, HID, INTER, 0, INTER, (long)HID * INTER);
            transpose_cvt_kernel<<<dim3(INTER / 64, HID / 64, ne), 256, 0, stream>>>(
                w3 + (size_t)g * HID * INTER, wt3, HID, INTER, 0, INTER, (long)HID * INTER);
            ffn1_kernel<<<NRB2 * ne * (INTER / BN), 512, 0, stream>>>(
                xbf, wt1, wt3, cnt + g, pbase + g, tokl, h, INTER / BN, 0);
        }
    } else {
        const int CN = 1024;
        for (int e = 0; e < NEXP; ++e) {
            for (int c = 0; c < INTER; c += CN) {
                ushort* wt1 = region;
                ushort* wt3 = region + (size_t)CN * HID;
                transpose_cvt_kernel<<<dim3(CN / 64, HID / 64, 1), 256, 0, stream>>>(
                    w1 + (size_t)e * HID * INTER, wt1, HID, INTER, c, CN, (long)HID * INTER);
                transpose_cvt_kernel<<<dim3(CN / 64, HID / 64, 1), 256, 0, stream>>>(
                    w3 + (size_t)e * HID * INTER, wt3, HID, INTER, c, CN, (long)HID * INTER);
                ffn1_kernel<<<NRB2 * (CN / BN), 512, 0, stream>>>(
                    xbf, wt1, wt3, cnt + e, pbase + e, tokl, h, CN / BN, c);
            }
        }
    }

    // ---- stage 2: transpose w2 + ffn2 ----
    if (region_bytes >= per_e2) {
        int EG = (int)(region_bytes / per_e2); if (EG > 8) EG = 8;
        for (int g = 0; g < NEXP; g += EG) {
            int ne = (NEXP - g < EG) ? (NEXP - g) : EG;
            ushort* wt2 = region;
            transpose_cvt_kernel<<<dim3(HID / 64, INTER / 64, ne), 256, 0, stream>>>(
                w2 + (size_t)g * INTER * HID, wt2, INTER, HID, 0, HID, (long)INTER * HID);
            ffn2_kernel<<<NRB2 * ne * (HID / BN), 512, 0, stream>>>(
                h, wt2, cnt + g, pbase + g, tokl, wgtl, out, HID / BN, 0);
        }
    } else {
        const int CN = 1024;
        for (int e = 0; e < NEXP; ++e) {
            for (int c = 0; c < HID; c += CN) {
                ushort* wt2 = region;
                transpose_cvt_kernel<<<dim3(CN / 64, INTER / 64, 1), 256, 0, stream>>>(
                    w2 + (size_t)e * INTER * HID, wt2, INTER, HID, c, CN, (long)INTER * HID);
                ffn2_kernel<<<NRB2 * (CN / BN), 512, 0, stream>>>(
                    h, wt2, cnt + e, pbase + e, tokl, wgtl, out, CN / BN, c);
            }
        }
    }
}